// Round 10
// baseline (1176.536 us; speedup 1.0000x reference)
//
#include <hip/hip_runtime.h>
#include <hip/hip_bf16.h>

// Problem constants (fixed by setup_inputs)
#define D     128
#define NLIT  32000
#define NCLA  64000
#define KLIT  3
#define NEDGE 192000
#define BGR   32
#define ITERS 4
#define LITS_PER_GRAPH 1000

typedef _Float16 f16x8 __attribute__((ext_vector_type(8)));
typedef float    f32x4 __attribute__((ext_vector_type(4)));

__device__ __forceinline__ float sigf(float x)  { return 1.f / (1.f + __expf(-x)); }
__device__ __forceinline__ float tanhft(float x){ return 1.f - 2.f / (__expf(2.f * x) + 1.f); }

// ---------------------------------------------------------------------------
// one-time conversions
// ---------------------------------------------------------------------------
__global__ void conv_x_kernel(const float* __restrict__ x, _Float16* __restrict__ o) {
    int t = blockIdx.x * blockDim.x + threadIdx.x;          // NLIT*16
    if (t >= NLIT * 16) return;
    const float* p = x + t * 8;
    f16x8 v;
#pragma unroll
    for (int i = 0; i < 8; ++i) v[i] = (_Float16)p[i];
    *(f16x8*)((_Float16*)o + t * 8) = v;
}

// Packed W layout: WcP[ch][qd][c][ln][t=g*4+dt][j]  (j: 8 f16 = one frag)
// A lane (qd,ln) in d-half c reads its 16 chunk-frags from 256 B contiguous.
__global__ void conv_wc_kernel(const float* __restrict__ Wih,
                               const float* __restrict__ Whh,
                               _Float16* __restrict__ WcP) {
    int n = blockIdx.x, k = threadIdx.x;                    // 512 x 256
    float v = (k < 128) ? Wih[n * 128 + k] : Whh[n * 128 + k - 128];
    int g = n >> 7, rem = n & 127, c = rem >> 6, dt = (rem >> 4) & 3, ln = rem & 15;
    int ch = k >> 5, qd = (k >> 3) & 3, j = k & 7;
    size_t off = (((((size_t)ch * 4 + qd) * 2 + c) * 16 + ln) * 16 + (g * 4 + dt)) * 8 + j;
    WcP[off] = (_Float16)v;
}

__global__ void conv_wl_kernel(const float* __restrict__ Wih,
                               const float* __restrict__ Whh,
                               _Float16* __restrict__ WlP) {
    int n = blockIdx.x, k = threadIdx.x;                    // 512 x 384
    float v = (k < 256) ? Wih[n * 256 + k] : Whh[n * 128 + k - 256];
    int g = n >> 7, rem = n & 127, c = rem >> 6, dt = (rem >> 4) & 3, ln = rem & 15;
    int ch = k >> 5, qd = (k >> 3) & 3, j = k & 7;
    size_t off = (((((size_t)ch * 4 + qd) * 2 + c) * 16 + ln) * 16 + (g * 4 + dt)) * 8 + j;
    WlP[off] = (_Float16)v;
}

// bias combine + hc0 (= C_w + C_b as f16, the iter-0 h_c broadcast row)
__global__ void conv_bias_kernel(const float* bih_c, const float* bhh_c, float* bc,
                                 const float* bih_l, const float* bhh_l, float* bl,
                                 const float* C_w, const float* C_b,
                                 _Float16* hc0g) {
    int t = threadIdx.x;                                    // 512
    bc[t] = bih_c[t] + bhh_c[t];
    bl[t] = bih_l[t] + bhh_l[t];
    if (t < 128) hc0g[t] = (_Float16)(C_w[t] + C_b[t]);
}

// ---------------------------------------------------------------------------
// CSR build: counts -> (block sums -> scan -> block-local scan) -> fill
// ---------------------------------------------------------------------------
__global__ void count_edges_kernel(const int* __restrict__ lit_idx,
                                   int* __restrict__ counts) {
    int e = blockIdx.x * blockDim.x + threadIdx.x;
    if (e < NEDGE) atomicAdd(&counts[lit_idx[e]], 1);
}

__global__ __launch_bounds__(256)
void block_sum_kernel(const int* __restrict__ counts, int* __restrict__ bsum) {
    int b = blockIdx.x, t = threadIdx.x;
    int v = counts[b * 256 + t];
    int lane = t & 63, w = t >> 6;
#pragma unroll
    for (int off = 32; off > 0; off >>= 1) v += __shfl_down(v, off, 64);
    __shared__ int ws[4];
    if (lane == 0) ws[w] = v;
    __syncthreads();
    if (t == 0) bsum[b] = ws[0] + ws[1] + ws[2] + ws[3];
}

__global__ void scan_bsum_kernel(const int* __restrict__ bsum,
                                 int* __restrict__ ebsum,
                                 int* __restrict__ starts) {
    __shared__ int s[128];
    int t = threadIdx.x;
    int v = (t < 125) ? bsum[t] : 0;
    s[t] = v;
    __syncthreads();
    for (int off = 1; off < 128; off <<= 1) {
        int y = (t >= off) ? s[t - off] : 0;
        __syncthreads();
        s[t] += y;
        __syncthreads();
    }
    if (t < 125) ebsum[t] = s[t] - v;       // exclusive
    if (t == 0) starts[NLIT] = NEDGE;
}

__global__ __launch_bounds__(256)
void scan_write_kernel(const int* __restrict__ counts,
                       const int* __restrict__ ebsum,
                       int* __restrict__ starts,
                       int* __restrict__ cursor) {
    int b = blockIdx.x, t = threadIdx.x;
    int idx = b * 256 + t;
    int v = counts[idx];
    int lane = t & 63, w = t >> 6;
    int x = v;
#pragma unroll
    for (int off = 1; off < 64; off <<= 1) {
        int y = __shfl_up(x, off, 64);
        if (lane >= off) x += y;
    }
    __shared__ int wsum[4];
    if (lane == 63) wsum[w] = x;
    __syncthreads();
    int woff = 0;
#pragma unroll
    for (int i = 0; i < 4; ++i) if (i < w) woff += wsum[i];
    int g = ebsum[b] + woff + x - v;        // exclusive prefix
    starts[idx] = g;
    cursor[idx] = g;
}

__global__ void fill_csr_kernel(const int* __restrict__ lit_idx,
                                const int* __restrict__ clause_idx,
                                int* __restrict__ cursor,
                                int* __restrict__ edge_clause) {
    int e = blockIdx.x * blockDim.x + threadIdx.x;
    if (e < NEDGE) {
        int l = lit_idx[e];
        int pos = atomicAdd(&cursor[l], 1);
        edge_clause[pos] = clause_idx[e];
    }
}

// ---------------------------------------------------------------------------
// msg_l[l][:] = sum over clauses of literal l of h_c16[clause][:]  (f16 io, fp32 acc)
// ---------------------------------------------------------------------------
__global__ void gather_msg_kernel(const _Float16* __restrict__ h_c16,
                                  _Float16* __restrict__ msg16,
                                  const int* __restrict__ starts,
                                  const int* __restrict__ edge_clause) {
    int t = blockIdx.x * blockDim.x + threadIdx.x;          // NLIT*16
    if (t >= NLIT * 16) return;
    int l = t >> 4;
    int off = (t & 15) * 8;
    int s = starts[l], e = starts[l + 1];
    float a[8];
#pragma unroll
    for (int i = 0; i < 8; ++i) a[i] = 0.f;
    for (int j = s; j < e; ++j) {
        f16x8 v = *(const f16x8*)&h_c16[(size_t)edge_clause[j] * D + off];
#pragma unroll
        for (int i = 0; i < 8; ++i) a[i] += (float)v[i];
    }
    f16x8 o;
#pragma unroll
    for (int i = 0; i < 8; ++i) o[i] = (_Float16)a[i];
    *(f16x8*)&msg16[(size_t)l * D + off] = o;
}

// ---------------------------------------------------------------------------
// Clause LSTM (MFMA), barrier-free: M=16 rows/WAVE, N=256 (4 gates x 64 d-half),
// K=256. No LDS, no __syncthreads. Each lane sources its own A-frag directly
// (gather3 via packed-f16 adds) and streams 16 contiguous B-frags/chunk from
// the lane-major packed W. acc = 64 VGPR -> 3 waves/SIMD without spill.
// ---------------------------------------------------------------------------
__global__ __launch_bounds__(256, 3)
void clause_mfma_kernel(const _Float16* __restrict__ h_l16,   // NLIT x 128
                        const _Float16* __restrict__ h_c_old, // NCLA x 128
                        _Float16* __restrict__ h_c_new,       // NCLA x 128
                        _Float16* __restrict__ c_c16,         // NCLA x 128 (f16 cell)
                        const _Float16* __restrict__ WcP,     // packed 512x256
                        const float* __restrict__ bc,         // 512
                        const _Float16* __restrict__ hc0g,    // 128 (iter-0 h_c row)
                        const int* __restrict__ lit_idx,
                        int first) {
    const int tid  = threadIdx.x;
    const int w    = tid >> 6;
    const int lane = tid & 63;
    const int qd   = lane >> 4;
    const int ln   = lane & 15;
    const int c    = (blockIdx.x >= (NCLA / 64)) ? 1 : 0;    // d-half (grouped for L1)
    const int row0 = (blockIdx.x - c * (NCLA / 64)) * 64;
    const int gm   = row0 + 16 * w + ln;                     // this lane's A row

    // A source pointers (lane-private)
    const int b3 = 3 * gm;
    const int li0 = lit_idx[b3 + 0], li1 = lit_idx[b3 + 1], li2 = lit_idx[b3 + 2];
    const _Float16* pa0 = h_l16 + (size_t)li0 * D + qd * 8;
    const _Float16* pa1 = h_l16 + (size_t)li1 * D + qd * 8;
    const _Float16* pa2 = h_l16 + (size_t)li2 * D + qd * 8;
    const _Float16* pcc = first ? (hc0g + qd * 8)
                                : (h_c_old + (size_t)gm * D + qd * 8);

    // B base: lane's packed-frag run for ch=0 (advance 16384 f16 per chunk)
    const _Float16* pb = WcP + ((((size_t)qd * 2 + c) * 16 + ln) * 128);

    f32x4 acc[16];
#pragma unroll
    for (int t = 0; t < 16; ++t) { acc[t][0]=0.f; acc[t][1]=0.f; acc[t][2]=0.f; acc[t][3]=0.f; }

#pragma unroll
    for (int ch = 0; ch < 8; ++ch) {
        f16x8 af;
        if (ch < 4) {
            f16x8 a0 = *(const f16x8*)(pa0 + ch * 32);
            f16x8 a1 = *(const f16x8*)(pa1 + ch * 32);
            f16x8 a2 = *(const f16x8*)(pa2 + ch * 32);
            af = a0 + a1 + a2;                       // packed f16 adds
        } else {
            af = *(const f16x8*)(pcc + (ch - 4) * 32);
        }
        const _Float16* pbc = pb + (size_t)ch * 16384;
#pragma unroll
        for (int t = 0; t < 16; ++t) {
            f16x8 bf = *(const f16x8*)(pbc + t * 8);
            acc[t] = __builtin_amdgcn_mfma_f32_16x16x32_f16(af, bf, acc[t], 0, 0, 0);
        }
    }

    // ---- fused LSTM epilogue: lane holds (i,f,g,o) for m=row0+16w+qd*4+r,
    // dcol = c*64 + dt*16 + ln   (t = g*4 + dt)
#pragma unroll
    for (int dt = 0; dt < 4; ++dt) {
        const int dcol = c * 64 + dt * 16 + ln;
        const float b0 = bc[dcol], b1 = bc[128 + dcol], b2 = bc[256 + dcol], b3f = bc[384 + dcol];
#pragma unroll
        for (int r = 0; r < 4; ++r) {
            int m = row0 + 16 * w + qd * 4 + r;
            size_t idx = (size_t)m * D + dcol;
            float gi = acc[0 * 4 + dt][r] + b0;
            float gf = acc[1 * 4 + dt][r] + b1;
            float gg = acc[2 * 4 + dt][r] + b2;
            float go = acc[3 * 4 + dt][r] + b3f;
            float cn = sigf(gi) * tanhft(gg);
            if (!first) cn += sigf(gf) * (float)c_c16[idx];
            float h  = sigf(go) * tanhft(cn);
            c_c16[idx]   = (_Float16)cn;
            h_c_new[idx] = (_Float16)h;
        }
    }
}

// ---------------------------------------------------------------------------
// Literal LSTM (MFMA), barrier-free: A = [msg_l | h_old[flip] | h_old], K=384.
// Same wave-autonomous structure, 12 chunks.
// ---------------------------------------------------------------------------
__global__ __launch_bounds__(256, 3)
void literal_mfma_kernel(const _Float16* __restrict__ h_old16, // NLIT x 128
                         const _Float16* __restrict__ msg16,   // NLIT x 128
                         _Float16* __restrict__ h_new16,       // NLIT x 128
                         float* __restrict__ h32,              // fp32 out (final iter)
                         _Float16* __restrict__ c_l16,         // NLIT x 128 (f16 cell)
                         const _Float16* __restrict__ WlP,     // packed 512x384
                         const float* __restrict__ bl,         // 512
                         const int* __restrict__ flip_perm,
                         int first) {
    const int tid  = threadIdx.x;
    const int w    = tid >> 6;
    const int lane = tid & 63;
    const int qd   = lane >> 4;
    const int ln   = lane & 15;
    const int c    = (blockIdx.x >= (NLIT / 64)) ? 1 : 0;
    const int row0 = (blockIdx.x - c * (NLIT / 64)) * 64;
    const int gm   = row0 + 16 * w + ln;

    const int fl = flip_perm[gm];
    const _Float16* pm = msg16   + (size_t)gm * D + qd * 8;   // ch 0..3
    const _Float16* pf = h_old16 + (size_t)fl * D + qd * 8;   // ch 4..7
    const _Float16* po = h_old16 + (size_t)gm * D + qd * 8;   // ch 8..11

    const _Float16* pb = WlP + ((((size_t)qd * 2 + c) * 16 + ln) * 128);

    f32x4 acc[16];
#pragma unroll
    for (int t = 0; t < 16; ++t) { acc[t][0]=0.f; acc[t][1]=0.f; acc[t][2]=0.f; acc[t][3]=0.f; }

#pragma unroll
    for (int ch = 0; ch < 12; ++ch) {
        f16x8 af;
        if (ch < 4)      af = *(const f16x8*)(pm + ch * 32);
        else if (ch < 8) af = *(const f16x8*)(pf + (ch - 4) * 32);
        else             af = *(const f16x8*)(po + (ch - 8) * 32);
        const _Float16* pbc = pb + (size_t)ch * 16384;
#pragma unroll
        for (int t = 0; t < 16; ++t) {
            f16x8 bf = *(const f16x8*)(pbc + t * 8);
            acc[t] = __builtin_amdgcn_mfma_f32_16x16x32_f16(af, bf, acc[t], 0, 0, 0);
        }
    }

#pragma unroll
    for (int dt = 0; dt < 4; ++dt) {
        const int dcol = c * 64 + dt * 16 + ln;
        const float b0 = bl[dcol], b1 = bl[128 + dcol], b2 = bl[256 + dcol], b3f = bl[384 + dcol];
#pragma unroll
        for (int r = 0; r < 4; ++r) {
            int m = row0 + 16 * w + qd * 4 + r;
            size_t idx = (size_t)m * D + dcol;
            float gi = acc[0 * 4 + dt][r] + b0;
            float gf = acc[1 * 4 + dt][r] + b1;
            float gg = acc[2 * 4 + dt][r] + b2;
            float go = acc[3 * 4 + dt][r] + b3f;
            float cn = sigf(gi) * tanhft(gg);
            if (!first) cn += sigf(gf) * (float)c_l16[idx];
            float h  = sigf(go) * tanhft(cn);
            c_l16[idx]   = (_Float16)cn;
            h_new16[idx] = (_Float16)h;
            if (h32) h32[idx] = h;
        }
    }
}

// ---------------------------------------------------------------------------
// votes stage 1: one wave per literal, no atomics.
// ---------------------------------------------------------------------------
__global__ __launch_bounds__(256)
void votes_stage1_kernel(const float* __restrict__ h_l,
                         const float* __restrict__ out_w,
                         const float* __restrict__ out_b,
                         float* __restrict__ votes_out) {
    int w    = threadIdx.x >> 6;            // wave in block
    int lane = threadIdx.x & 63;
    int l    = blockIdx.x * 4 + w;          // grid = NLIT/4
    if (l >= NLIT) return;
    const float2 v = *(const float2*)&h_l[(size_t)l * D + lane * 2];
    const float2 ww = *(const float2*)&out_w[lane * 2];
    float p = v.x * ww.x + v.y * ww.y;
#pragma unroll
    for (int off = 32; off > 0; off >>= 1) p += __shfl_down(p, off, 64);
    if (lane == 0) votes_out[l] = p + out_b[0];
}

// votes stage 2: one block per graph, sum 1000 contiguous votes -> mean
__global__ __launch_bounds__(256)
void votes_stage2_kernel(const float* __restrict__ votes,
                         float* __restrict__ out0) {
    int b = blockIdx.x;                     // 32 graphs
    int t = threadIdx.x;
    const float* base = votes + (size_t)b * LITS_PER_GRAPH;
    float s = 0.f;
    for (int i = t; i < LITS_PER_GRAPH; i += 256) s += base[i];
#pragma unroll
    for (int off = 32; off > 0; off >>= 1) s += __shfl_down(s, off, 64);
    __shared__ float ws[4];
    if ((t & 63) == 0) ws[t >> 6] = s;
    __syncthreads();
    if (t == 0) out0[b] = (ws[0] + ws[1] + ws[2] + ws[3]) / (float)LITS_PER_GRAPH;
}

// ---------------------------------------------------------------------------
extern "C" void kernel_launch(void* const* d_in, const int* in_sizes, int n_in,
                              void* d_out, int out_size, void* d_ws, size_t ws_size,
                              hipStream_t stream) {
    (void)in_sizes; (void)n_in; (void)out_size; (void)ws_size;

    const float* x_unk  = (const float*)d_in[0];
    const float* C_w    = (const float*)d_in[1];
    const float* C_b    = (const float*)d_in[2];
    const float* Wih_lc = (const float*)d_in[3];
    const float* Whh_lc = (const float*)d_in[4];
    const float* bih_lc = (const float*)d_in[5];
    const float* bhh_lc = (const float*)d_in[6];
    const float* Wih_cl = (const float*)d_in[7];
    const float* Whh_cl = (const float*)d_in[8];
    const float* bih_cl = (const float*)d_in[9];
    const float* bhh_cl = (const float*)d_in[10];
    const float* out_w  = (const float*)d_in[11];
    const float* out_b  = (const float*)d_in[12];
    const int* lit_idx    = (const int*)d_in[13];
    const int* clause_idx = (const int*)d_in[14];
    const int* flip_perm  = (const int*)d_in[16];

    // ---- workspace layout (bytes, 256-aligned chunks)
    char* W = (char*)d_ws;
    size_t off = 0;
    auto alloc = [&](size_t bytes) { char* p = W + off; off = (off + bytes + 255) & ~(size_t)255; return p; };
    _Float16* h_l16_0 = (_Float16*)alloc((size_t)NLIT * D * 2);
    _Float16* h_l16_1 = (_Float16*)alloc((size_t)NLIT * D * 2);
    _Float16* h_c16_0 = (_Float16*)alloc((size_t)NCLA * D * 2);
    _Float16* h_c16_1 = (_Float16*)alloc((size_t)NCLA * D * 2);
    _Float16* msg16   = (_Float16*)alloc((size_t)NLIT * D * 2);
    _Float16* c_l16   = (_Float16*)alloc((size_t)NLIT * D * 2);
    _Float16* c_c16   = (_Float16*)alloc((size_t)NCLA * D * 2);
    _Float16* Wc16    = (_Float16*)alloc(512 * 256 * 2);
    _Float16* Wl16    = (_Float16*)alloc(512 * 384 * 2);
    float*    bc      = (float*)  alloc(512 * 4);
    float*    bl      = (float*)  alloc(512 * 4);
    _Float16* hc0g    = (_Float16*)alloc(128 * 2);
    int* counts       = (int*)alloc((size_t)NLIT * 4);
    int* starts       = (int*)alloc((size_t)(NLIT + 1) * 4);
    int* cursor       = (int*)alloc((size_t)NLIT * 4);
    int* edge_clause  = (int*)alloc((size_t)NEDGE * 4);
    int* bsum         = (int*)alloc(128 * 4);
    int* ebsum        = (int*)alloc(128 * 4);

    float* out       = (float*)d_out;
    float* out_votes = out + BGR;
    float* out_hl    = out + BGR + NLIT;

    // counts must start at zero for the atomic histogram
    hipMemsetAsync(counts, 0, (size_t)NLIT * 4, stream);

    // ---- one-time conversions
    conv_x_kernel<<<(NLIT * 16 + 255) / 256, 256, 0, stream>>>(x_unk, h_l16_0);
    conv_wc_kernel<<<512, 256, 0, stream>>>(Wih_lc, Whh_lc, Wc16);
    conv_wl_kernel<<<512, 384, 0, stream>>>(Wih_cl, Whh_cl, Wl16);
    conv_bias_kernel<<<1, 512, 0, stream>>>(bih_lc, bhh_lc, bc, bih_cl, bhh_cl, bl,
                                            C_w, C_b, hc0g);

    // ---- CSR build (parallel scan)
    count_edges_kernel<<<(NEDGE + 255) / 256, 256, 0, stream>>>(lit_idx, counts);
    block_sum_kernel<<<NLIT / 256, 256, 0, stream>>>(counts, bsum);
    scan_bsum_kernel<<<1, 128, 0, stream>>>(bsum, ebsum, starts);
    scan_write_kernel<<<NLIT / 256, 256, 0, stream>>>(counts, ebsum, starts, cursor);
    fill_csr_kernel<<<(NEDGE + 255) / 256, 256, 0, stream>>>(lit_idx, clause_idx,
                                                             cursor, edge_clause);

    // ---- message-passing iterations (h_l and h_c ping-pong in f16)
    const _Float16* hl_old[ITERS] = {h_l16_0, h_l16_1, h_l16_0, h_l16_1};
    _Float16*       hl_new[ITERS] = {h_l16_1, h_l16_0, h_l16_1, h_l16_0};
    const _Float16* hc_old[ITERS] = {h_c16_0, h_c16_1, h_c16_0, h_c16_1};
    _Float16*       hc_new[ITERS] = {h_c16_1, h_c16_0, h_c16_1, h_c16_0};

    for (int it = 0; it < ITERS; ++it) {
        clause_mfma_kernel<<<(NCLA / 64) * 2, 256, 0, stream>>>(
            hl_old[it], hc_old[it], hc_new[it], c_c16, Wc16, bc, hc0g, lit_idx,
            it == 0 ? 1 : 0);
        gather_msg_kernel<<<(NLIT * 16 + 255) / 256, 256, 0, stream>>>(
            hc_new[it], msg16, starts, edge_clause);
        literal_mfma_kernel<<<(NLIT / 64) * 2, 256, 0, stream>>>(
            hl_old[it], msg16, hl_new[it],
            (it == ITERS - 1) ? out_hl : (float*)nullptr,
            c_l16, Wl16, bl, flip_perm,
            it == 0 ? 1 : 0);
    }

    votes_stage1_kernel<<<NLIT / 4, 256, 0, stream>>>(out_hl, out_w, out_b, out_votes);
    votes_stage2_kernel<<<BGR, 256, 0, stream>>>(out_votes, out);
}

// Round 11
// 464.740 us; speedup vs baseline: 2.5316x; 2.5316x over previous
//
#include <hip/hip_runtime.h>
#include <hip/hip_bf16.h>

// Problem constants (fixed by setup_inputs)
#define D     128
#define NLIT  32000
#define NCLA  64000
#define KLIT  3
#define NEDGE 192000
#define BGR   32
#define ITERS 4
#define LITS_PER_GRAPH 1000

typedef _Float16 f16x8 __attribute__((ext_vector_type(8)));
typedef float    f32x4 __attribute__((ext_vector_type(4)));

#define TSTRIDE 40   // LDS A-tile row stride in f16

__device__ __forceinline__ float sigf(float x)  { return 1.f / (1.f + __expf(-x)); }
__device__ __forceinline__ float tanhft(float x){ return 1.f - 2.f / (__expf(2.f * x) + 1.f); }

// ---------------------------------------------------------------------------
// one-time conversions
// ---------------------------------------------------------------------------
__global__ void conv_x_kernel(const float* __restrict__ x, _Float16* __restrict__ o) {
    int t = blockIdx.x * blockDim.x + threadIdx.x;          // NLIT*16
    if (t >= NLIT * 16) return;
    const float* p = x + t * 8;
    f16x8 v;
#pragma unroll
    for (int i = 0; i < 8; ++i) v[i] = (_Float16)p[i];
    *(f16x8*)((_Float16*)o + t * 8) = v;
}

// Packed W: off = (((ch*4+qd)*128 + dcol)*4 + g)*8 + j
// lane (w,qd,ln) with dcol=16w+ln reads its 4 gate-frags from 64 B contiguous.
__global__ void conv_wc_kernel(const float* __restrict__ Wih,
                               const float* __restrict__ Whh,
                               _Float16* __restrict__ WcP) {
    int n = blockIdx.x, k = threadIdx.x;                    // 512 x 256
    float v = (k < 128) ? Wih[n * 128 + k] : Whh[n * 128 + k - 128];
    int g = n >> 7, dcol = n & 127;
    int ch = k >> 5, qd = (k >> 3) & 3, j = k & 7;
    size_t off = ((((size_t)ch * 4 + qd) * 128 + dcol) * 4 + g) * 8 + j;
    WcP[off] = (_Float16)v;
}

__global__ void conv_wl_kernel(const float* __restrict__ Wih,
                               const float* __restrict__ Whh,
                               _Float16* __restrict__ WlP) {
    int n = blockIdx.x, k = threadIdx.x;                    // 512 x 384
    float v = (k < 256) ? Wih[n * 256 + k] : Whh[n * 128 + k - 256];
    int g = n >> 7, dcol = n & 127;
    int ch = k >> 5, qd = (k >> 3) & 3, j = k & 7;
    size_t off = ((((size_t)ch * 4 + qd) * 128 + dcol) * 4 + g) * 8 + j;
    WlP[off] = (_Float16)v;
}

// bias combine + hc0 (= C_w + C_b as f16, the iter-0 h_c broadcast row)
__global__ void conv_bias_kernel(const float* bih_c, const float* bhh_c, float* bc,
                                 const float* bih_l, const float* bhh_l, float* bl,
                                 const float* C_w, const float* C_b,
                                 _Float16* hc0g) {
    int t = threadIdx.x;                                    // 512
    bc[t] = bih_c[t] + bhh_c[t];
    bl[t] = bih_l[t] + bhh_l[t];
    if (t < 128) hc0g[t] = (_Float16)(C_w[t] + C_b[t]);
}

// ---------------------------------------------------------------------------
// CSR build: counts -> (block sums -> scan -> block-local scan) -> fill
// ---------------------------------------------------------------------------
__global__ void count_edges_kernel(const int* __restrict__ lit_idx,
                                   int* __restrict__ counts) {
    int e = blockIdx.x * blockDim.x + threadIdx.x;
    if (e < NEDGE) atomicAdd(&counts[lit_idx[e]], 1);
}

__global__ __launch_bounds__(256)
void block_sum_kernel(const int* __restrict__ counts, int* __restrict__ bsum) {
    int b = blockIdx.x, t = threadIdx.x;
    int v = counts[b * 256 + t];
    int lane = t & 63, w = t >> 6;
#pragma unroll
    for (int off = 32; off > 0; off >>= 1) v += __shfl_down(v, off, 64);
    __shared__ int ws[4];
    if (lane == 0) ws[w] = v;
    __syncthreads();
    if (t == 0) bsum[b] = ws[0] + ws[1] + ws[2] + ws[3];
}

__global__ void scan_bsum_kernel(const int* __restrict__ bsum,
                                 int* __restrict__ ebsum,
                                 int* __restrict__ starts) {
    __shared__ int s[128];
    int t = threadIdx.x;
    int v = (t < 125) ? bsum[t] : 0;
    s[t] = v;
    __syncthreads();
    for (int off = 1; off < 128; off <<= 1) {
        int y = (t >= off) ? s[t - off] : 0;
        __syncthreads();
        s[t] += y;
        __syncthreads();
    }
    if (t < 125) ebsum[t] = s[t] - v;       // exclusive
    if (t == 0) starts[NLIT] = NEDGE;
}

__global__ __launch_bounds__(256)
void scan_write_kernel(const int* __restrict__ counts,
                       const int* __restrict__ ebsum,
                       int* __restrict__ starts,
                       int* __restrict__ cursor) {
    int b = blockIdx.x, t = threadIdx.x;
    int idx = b * 256 + t;
    int v = counts[idx];
    int lane = t & 63, w = t >> 6;
    int x = v;
#pragma unroll
    for (int off = 1; off < 64; off <<= 1) {
        int y = __shfl_up(x, off, 64);
        if (lane >= off) x += y;
    }
    __shared__ int wsum[4];
    if (lane == 63) wsum[w] = x;
    __syncthreads();
    int woff = 0;
#pragma unroll
    for (int i = 0; i < 4; ++i) if (i < w) woff += wsum[i];
    int g = ebsum[b] + woff + x - v;        // exclusive prefix
    starts[idx] = g;
    cursor[idx] = g;
}

__global__ void fill_csr_kernel(const int* __restrict__ lit_idx,
                                const int* __restrict__ clause_idx,
                                int* __restrict__ cursor,
                                int* __restrict__ edge_clause) {
    int e = blockIdx.x * blockDim.x + threadIdx.x;
    if (e < NEDGE) {
        int l = lit_idx[e];
        int pos = atomicAdd(&cursor[l], 1);
        edge_clause[pos] = clause_idx[e];
    }
}

// ---------------------------------------------------------------------------
// msg_l[l][:] = sum over clauses of literal l of h_c16[clause][:]  (f16 io, fp32 acc)
// ---------------------------------------------------------------------------
__global__ void gather_msg_kernel(const _Float16* __restrict__ h_c16,
                                  _Float16* __restrict__ msg16,
                                  const int* __restrict__ starts,
                                  const int* __restrict__ edge_clause) {
    int t = blockIdx.x * blockDim.x + threadIdx.x;          // NLIT*16
    if (t >= NLIT * 16) return;
    int l = t >> 4;
    int off = (t & 15) * 8;
    int s = starts[l], e = starts[l + 1];
    float a[8];
#pragma unroll
    for (int i = 0; i < 8; ++i) a[i] = 0.f;
    for (int j = s; j < e; ++j) {
        f16x8 v = *(const f16x8*)&h_c16[(size_t)edge_clause[j] * D + off];
#pragma unroll
        for (int i = 0; i < 8; ++i) a[i] += (float)v[i];
    }
    f16x8 o;
#pragma unroll
    for (int i = 0; i < 8; ++i) o[i] = (_Float16)a[i];
    *(f16x8*)&msg16[(size_t)l * D + off] = o;
}

// ---------------------------------------------------------------------------
// Clause LSTM (MFMA), FULL-N: 512 thr (8 waves), M=64 rows/block, N=512.
// Wave w owns d-cols {16w+ln} for ALL 4 gates -> acc[4R][4g]=64 regs, LSTM
// quadruple in-register. A double-buffered in LDS (one barrier/chunk), staged
// by threads<256; B direct-global (4 frags/lane/chunk = 16 VGPRs) from
// lane-major packed W. c-state in lane-major blob (coalesced b128).
// ---------------------------------------------------------------------------
__global__ __launch_bounds__(512, 3)
void clause_mfma_kernel(const _Float16* __restrict__ h_l16,   // NLIT x 128
                        const _Float16* __restrict__ h_c_old, // NCLA x 128
                        _Float16* __restrict__ h_c_new,       // NCLA x 128
                        _Float16* __restrict__ c_blob,        // NCLA*128 lane-major
                        const _Float16* __restrict__ WcP,     // packed 512x256
                        const float* __restrict__ bc,         // 512
                        const _Float16* __restrict__ hc0g,    // 128 (iter-0 h_c row)
                        const int* __restrict__ lit_idx,
                        int first) {
    __shared__ _Float16 At[2][64 * TSTRIDE];

    const int tid  = threadIdx.x;
    const int w    = tid >> 6;
    const int lane = tid & 63;
    const int qd   = lane >> 4;
    const int ln   = lane & 15;
    const int row0 = blockIdx.x * 64;
    const int dcol = 16 * w + ln;

    // ---- B pointer (lane-major packed; 4 gate frags at +0,+8,+16,+24 f16)
    const _Float16* pb = WcP + ((size_t)qd * 128 + dcol) * 32;

    // ---- A staging role (threads < 256)
    const int m    = tid >> 2;          // 0..127 but only <256 used -> 0..63
    const int col8 = (tid & 3) * 8;
    const _Float16 *pa0 = nullptr, *pa1 = nullptr, *pa2 = nullptr, *pcc = nullptr;
    if (tid < 256) {
        int b3 = 3 * (row0 + m);
        pa0 = h_l16 + (size_t)lit_idx[b3 + 0] * D + col8;
        pa1 = h_l16 + (size_t)lit_idx[b3 + 1] * D + col8;
        pa2 = h_l16 + (size_t)lit_idx[b3 + 2] * D + col8;
        pcc = first ? (hc0g + col8) : (h_c_old + (size_t)(row0 + m) * D + col8);
    }

    // ---- prefetch ch 0
    f16x8 ldB0, ldB1, ldB2, ldB3, ldG0, ldG1, ldG2;
    ldB0 = *(const f16x8*)(pb + 0);
    ldB1 = *(const f16x8*)(pb + 8);
    ldB2 = *(const f16x8*)(pb + 16);
    ldB3 = *(const f16x8*)(pb + 24);
    if (tid < 256) {
        ldG0 = *(const f16x8*)pa0; pa0 += 32;
        ldG1 = *(const f16x8*)pa1; pa1 += 32;
        ldG2 = *(const f16x8*)pa2; pa2 += 32;
    }

    f32x4 acc[4][4];
#pragma unroll
    for (int R = 0; R < 4; ++R)
#pragma unroll
        for (int g = 0; g < 4; ++g) { acc[R][g][0]=0.f; acc[R][g][1]=0.f; acc[R][g][2]=0.f; acc[R][g][3]=0.f; }

    for (int ch = 0; ch < 8; ++ch) {
        _Float16* buf = (_Float16*)At[ch & 1];
        if (tid < 256) {
            f16x8 o = (ch < 4) ? (f16x8)(ldG0 + ldG1 + ldG2) : ldG0;
            *(f16x8*)&buf[m * TSTRIDE + col8] = o;
        }
        f16x8 bf0 = ldB0, bf1 = ldB1, bf2 = ldB2, bf3 = ldB3;
        // ---- prefetch ch+1
        if (ch < 7) {
            const _Float16* pbn = pb + (size_t)(ch + 1) * 16384;
            ldB0 = *(const f16x8*)(pbn + 0);
            ldB1 = *(const f16x8*)(pbn + 8);
            ldB2 = *(const f16x8*)(pbn + 16);
            ldB3 = *(const f16x8*)(pbn + 24);
            if (tid < 256) {
                if (ch + 1 < 4) {
                    ldG0 = *(const f16x8*)pa0; pa0 += 32;
                    ldG1 = *(const f16x8*)pa1; pa1 += 32;
                    ldG2 = *(const f16x8*)pa2; pa2 += 32;
                } else if (first) {
                    ldG0 = *(const f16x8*)(hc0g + (ch + 1 - 4) * 32 + col8);
                } else {
                    ldG0 = *(const f16x8*)pcc; pcc += 32;
                }
            }
        }
        __syncthreads();
        f16x8 af[4];
#pragma unroll
        for (int R = 0; R < 4; ++R)
            af[R] = *(const f16x8*)&buf[(16 * R + ln) * TSTRIDE + qd * 8];
#pragma unroll
        for (int R = 0; R < 4; ++R) {
            acc[R][0] = __builtin_amdgcn_mfma_f32_16x16x32_f16(af[R], bf0, acc[R][0], 0, 0, 0);
            acc[R][1] = __builtin_amdgcn_mfma_f32_16x16x32_f16(af[R], bf1, acc[R][1], 0, 0, 0);
            acc[R][2] = __builtin_amdgcn_mfma_f32_16x16x32_f16(af[R], bf2, acc[R][2], 0, 0, 0);
            acc[R][3] = __builtin_amdgcn_mfma_f32_16x16x32_f16(af[R], bf3, acc[R][3], 0, 0, 0);
        }
    }

    // ---- fused LSTM epilogue; c-state via lane-major blob (2x b128)
    _Float16* cb = c_blob + ((size_t)blockIdx.x * 512 + tid) * 16;
    f16x8 cold0, cold1;
    if (!first) { cold0 = *(const f16x8*)cb; cold1 = *(const f16x8*)(cb + 8); }
    const float b0 = bc[dcol], b1 = bc[128 + dcol], b2 = bc[256 + dcol], b3f = bc[384 + dcol];
    f16x8 cnew0, cnew1;
#pragma unroll
    for (int R = 0; R < 4; ++R) {
#pragma unroll
        for (int r = 0; r < 4; ++r) {
            int i = R * 4 + r;
            int mm = row0 + 16 * R + qd * 4 + r;
            float gi = acc[R][0][r] + b0;
            float gf = acc[R][1][r] + b1;
            float gg = acc[R][2][r] + b2;
            float go = acc[R][3][r] + b3f;
            float cn = sigf(gi) * tanhft(gg);
            if (!first) cn += sigf(gf) * (float)((i < 8) ? cold0[i & 7] : cold1[i & 7]);
            float h  = sigf(go) * tanhft(cn);
            if (i < 8) cnew0[i & 7] = (_Float16)cn; else cnew1[i & 7] = (_Float16)cn;
            h_c_new[(size_t)mm * D + dcol] = (_Float16)h;
        }
    }
    *(f16x8*)cb = cnew0;
    *(f16x8*)(cb + 8) = cnew1;
}

// ---------------------------------------------------------------------------
// Literal LSTM (MFMA), FULL-N: A = [msg_l | h_old[flip] | h_old], K=384.
// ---------------------------------------------------------------------------
__global__ __launch_bounds__(512, 3)
void literal_mfma_kernel(const _Float16* __restrict__ h_old16, // NLIT x 128
                         const _Float16* __restrict__ msg16,   // NLIT x 128
                         _Float16* __restrict__ h_new16,       // NLIT x 128
                         float* __restrict__ h32,              // fp32 out (final iter)
                         _Float16* __restrict__ c_blob,        // NLIT*128 lane-major
                         const _Float16* __restrict__ WlP,     // packed 512x384
                         const float* __restrict__ bl,         // 512
                         const int* __restrict__ flip_perm,
                         int first) {
    __shared__ _Float16 At[2][64 * TSTRIDE];

    const int tid  = threadIdx.x;
    const int w    = tid >> 6;
    const int lane = tid & 63;
    const int qd   = lane >> 4;
    const int ln   = lane & 15;
    const int row0 = blockIdx.x * 64;
    const int dcol = 16 * w + ln;

    const _Float16* pb = WlP + ((size_t)qd * 128 + dcol) * 32;

    const int m    = tid >> 2;
    const int col8 = (tid & 3) * 8;
    const _Float16 *cur = nullptr, *pf = nullptr, *po = nullptr;
    if (tid < 256) {
        pf  = h_old16 + (size_t)flip_perm[row0 + m] * D + col8;
        po  = h_old16 + (size_t)(row0 + m) * D + col8;
        cur = msg16   + (size_t)(row0 + m) * D + col8;
    }

    f16x8 ldB0, ldB1, ldB2, ldB3, ldA;
    ldB0 = *(const f16x8*)(pb + 0);
    ldB1 = *(const f16x8*)(pb + 8);
    ldB2 = *(const f16x8*)(pb + 16);
    ldB3 = *(const f16x8*)(pb + 24);
    if (tid < 256) { ldA = *(const f16x8*)cur; cur += 32; }

    f32x4 acc[4][4];
#pragma unroll
    for (int R = 0; R < 4; ++R)
#pragma unroll
        for (int g = 0; g < 4; ++g) { acc[R][g][0]=0.f; acc[R][g][1]=0.f; acc[R][g][2]=0.f; acc[R][g][3]=0.f; }

    for (int ch = 0; ch < 12; ++ch) {
        _Float16* buf = (_Float16*)At[ch & 1];
        if (tid < 256) *(f16x8*)&buf[m * TSTRIDE + col8] = ldA;
        f16x8 bf0 = ldB0, bf1 = ldB1, bf2 = ldB2, bf3 = ldB3;
        if (ch < 11) {
            const _Float16* pbn = pb + (size_t)(ch + 1) * 16384;
            ldB0 = *(const f16x8*)(pbn + 0);
            ldB1 = *(const f16x8*)(pbn + 8);
            ldB2 = *(const f16x8*)(pbn + 16);
            ldB3 = *(const f16x8*)(pbn + 24);
            if (tid < 256) {
                if (ch + 1 == 4)      cur = pf;
                else if (ch + 1 == 8) cur = po;
                ldA = *(const f16x8*)cur; cur += 32;
            }
        }
        __syncthreads();
        f16x8 af[4];
#pragma unroll
        for (int R = 0; R < 4; ++R)
            af[R] = *(const f16x8*)&buf[(16 * R + ln) * TSTRIDE + qd * 8];
#pragma unroll
        for (int R = 0; R < 4; ++R) {
            acc[R][0] = __builtin_amdgcn_mfma_f32_16x16x32_f16(af[R], bf0, acc[R][0], 0, 0, 0);
            acc[R][1] = __builtin_amdgcn_mfma_f32_16x16x32_f16(af[R], bf1, acc[R][1], 0, 0, 0);
            acc[R][2] = __builtin_amdgcn_mfma_f32_16x16x32_f16(af[R], bf2, acc[R][2], 0, 0, 0);
            acc[R][3] = __builtin_amdgcn_mfma_f32_16x16x32_f16(af[R], bf3, acc[R][3], 0, 0, 0);
        }
    }

    _Float16* cb = c_blob + ((size_t)blockIdx.x * 512 + tid) * 16;
    f16x8 cold0, cold1;
    if (!first) { cold0 = *(const f16x8*)cb; cold1 = *(const f16x8*)(cb + 8); }
    const float b0 = bl[dcol], b1 = bl[128 + dcol], b2 = bl[256 + dcol], b3f = bl[384 + dcol];
    f16x8 cnew0, cnew1;
#pragma unroll
    for (int R = 0; R < 4; ++R) {
#pragma unroll
        for (int r = 0; r < 4; ++r) {
            int i = R * 4 + r;
            int mm = row0 + 16 * R + qd * 4 + r;
            size_t idx = (size_t)mm * D + dcol;
            float gi = acc[R][0][r] + b0;
            float gf = acc[R][1][r] + b1;
            float gg = acc[R][2][r] + b2;
            float go = acc[R][3][r] + b3f;
            float cn = sigf(gi) * tanhft(gg);
            if (!first) cn += sigf(gf) * (float)((i < 8) ? cold0[i & 7] : cold1[i & 7]);
            float h  = sigf(go) * tanhft(cn);
            if (i < 8) cnew0[i & 7] = (_Float16)cn; else cnew1[i & 7] = (_Float16)cn;
            h_new16[idx] = (_Float16)h;
            if (h32) h32[idx] = h;
        }
    }
    *(f16x8*)cb = cnew0;
    *(f16x8*)(cb + 8) = cnew1;
}

// ---------------------------------------------------------------------------
// votes stage 1: one wave per literal, no atomics.
// ---------------------------------------------------------------------------
__global__ __launch_bounds__(256)
void votes_stage1_kernel(const float* __restrict__ h_l,
                         const float* __restrict__ out_w,
                         const float* __restrict__ out_b,
                         float* __restrict__ votes_out) {
    int w    = threadIdx.x >> 6;            // wave in block
    int lane = threadIdx.x & 63;
    int l    = blockIdx.x * 4 + w;          // grid = NLIT/4
    if (l >= NLIT) return;
    const float2 v = *(const float2*)&h_l[(size_t)l * D + lane * 2];
    const float2 ww = *(const float2*)&out_w[lane * 2];
    float p = v.x * ww.x + v.y * ww.y;
#pragma unroll
    for (int off = 32; off > 0; off >>= 1) p += __shfl_down(p, off, 64);
    if (lane == 0) votes_out[l] = p + out_b[0];
}

// votes stage 2: one block per graph, sum 1000 contiguous votes -> mean
__global__ __launch_bounds__(256)
void votes_stage2_kernel(const float* __restrict__ votes,
                         float* __restrict__ out0) {
    int b = blockIdx.x;                     // 32 graphs
    int t = threadIdx.x;
    const float* base = votes + (size_t)b * LITS_PER_GRAPH;
    float s = 0.f;
    for (int i = t; i < LITS_PER_GRAPH; i += 256) s += base[i];
#pragma unroll
    for (int off = 32; off > 0; off >>= 1) s += __shfl_down(s, off, 64);
    __shared__ float ws[4];
    if ((t & 63) == 0) ws[t >> 6] = s;
    __syncthreads();
    if (t == 0) out0[b] = (ws[0] + ws[1] + ws[2] + ws[3]) / (float)LITS_PER_GRAPH;
}

// ---------------------------------------------------------------------------
extern "C" void kernel_launch(void* const* d_in, const int* in_sizes, int n_in,
                              void* d_out, int out_size, void* d_ws, size_t ws_size,
                              hipStream_t stream) {
    (void)in_sizes; (void)n_in; (void)out_size; (void)ws_size;

    const float* x_unk  = (const float*)d_in[0];
    const float* C_w    = (const float*)d_in[1];
    const float* C_b    = (const float*)d_in[2];
    const float* Wih_lc = (const float*)d_in[3];
    const float* Whh_lc = (const float*)d_in[4];
    const float* bih_lc = (const float*)d_in[5];
    const float* bhh_lc = (const float*)d_in[6];
    const float* Wih_cl = (const float*)d_in[7];
    const float* Whh_cl = (const float*)d_in[8];
    const float* bih_cl = (const float*)d_in[9];
    const float* bhh_cl = (const float*)d_in[10];
    const float* out_w  = (const float*)d_in[11];
    const float* out_b  = (const float*)d_in[12];
    const int* lit_idx    = (const int*)d_in[13];
    const int* clause_idx = (const int*)d_in[14];
    const int* flip_perm  = (const int*)d_in[16];

    // ---- workspace layout (bytes, 256-aligned chunks)
    char* W = (char*)d_ws;
    size_t off = 0;
    auto alloc = [&](size_t bytes) { char* p = W + off; off = (off + bytes + 255) & ~(size_t)255; return p; };
    _Float16* h_l16_0 = (_Float16*)alloc((size_t)NLIT * D * 2);
    _Float16* h_l16_1 = (_Float16*)alloc((size_t)NLIT * D * 2);
    _Float16* h_c16_0 = (_Float16*)alloc((size_t)NCLA * D * 2);
    _Float16* h_c16_1 = (_Float16*)alloc((size_t)NCLA * D * 2);
    _Float16* msg16   = (_Float16*)alloc((size_t)NLIT * D * 2);
    _Float16* c_l16   = (_Float16*)alloc((size_t)NLIT * D * 2);   // lane-major blob
    _Float16* c_c16   = (_Float16*)alloc((size_t)NCLA * D * 2);   // lane-major blob
    _Float16* Wc16    = (_Float16*)alloc(512 * 256 * 2);
    _Float16* Wl16    = (_Float16*)alloc(512 * 384 * 2);
    float*    bc      = (float*)  alloc(512 * 4);
    float*    bl      = (float*)  alloc(512 * 4);
    _Float16* hc0g    = (_Float16*)alloc(128 * 2);
    int* counts       = (int*)alloc((size_t)NLIT * 4);
    int* starts       = (int*)alloc((size_t)(NLIT + 1) * 4);
    int* cursor       = (int*)alloc((size_t)NLIT * 4);
    int* edge_clause  = (int*)alloc((size_t)NEDGE * 4);
    int* bsum         = (int*)alloc(128 * 4);
    int* ebsum        = (int*)alloc(128 * 4);

    float* out       = (float*)d_out;
    float* out_votes = out + BGR;
    float* out_hl    = out + BGR + NLIT;

    // counts must start at zero for the atomic histogram
    hipMemsetAsync(counts, 0, (size_t)NLIT * 4, stream);

    // ---- one-time conversions
    conv_x_kernel<<<(NLIT * 16 + 255) / 256, 256, 0, stream>>>(x_unk, h_l16_0);
    conv_wc_kernel<<<512, 256, 0, stream>>>(Wih_lc, Whh_lc, Wc16);
    conv_wl_kernel<<<512, 384, 0, stream>>>(Wih_cl, Whh_cl, Wl16);
    conv_bias_kernel<<<1, 512, 0, stream>>>(bih_lc, bhh_lc, bc, bih_cl, bhh_cl, bl,
                                            C_w, C_b, hc0g);

    // ---- CSR build (parallel scan)
    count_edges_kernel<<<(NEDGE + 255) / 256, 256, 0, stream>>>(lit_idx, counts);
    block_sum_kernel<<<NLIT / 256, 256, 0, stream>>>(counts, bsum);
    scan_bsum_kernel<<<1, 128, 0, stream>>>(bsum, ebsum, starts);
    scan_write_kernel<<<NLIT / 256, 256, 0, stream>>>(counts, ebsum, starts, cursor);
    fill_csr_kernel<<<(NEDGE + 255) / 256, 256, 0, stream>>>(lit_idx, clause_idx,
                                                             cursor, edge_clause);

    // ---- message-passing iterations (h_l and h_c ping-pong in f16)
    const _Float16* hl_old[ITERS] = {h_l16_0, h_l16_1, h_l16_0, h_l16_1};
    _Float16*       hl_new[ITERS] = {h_l16_1, h_l16_0, h_l16_1, h_l16_0};
    const _Float16* hc_old[ITERS] = {h_c16_0, h_c16_1, h_c16_0, h_c16_1};
    _Float16*       hc_new[ITERS] = {h_c16_1, h_c16_0, h_c16_1, h_c16_0};

    for (int it = 0; it < ITERS; ++it) {
        clause_mfma_kernel<<<NCLA / 64, 512, 0, stream>>>(
            hl_old[it], hc_old[it], hc_new[it], c_c16, Wc16, bc, hc0g, lit_idx,
            it == 0 ? 1 : 0);
        gather_msg_kernel<<<(NLIT * 16 + 255) / 256, 256, 0, stream>>>(
            hc_new[it], msg16, starts, edge_clause);
        literal_mfma_kernel<<<NLIT / 64, 512, 0, stream>>>(
            hl_old[it], msg16, hl_new[it],
            (it == ITERS - 1) ? out_hl : (float*)nullptr,
            c_l16, Wl16, bl, flip_perm,
            it == 0 ? 1 : 0);
    }

    votes_stage1_kernel<<<NLIT / 4, 256, 0, stream>>>(out_hl, out_w, out_b, out_votes);
    votes_stage2_kernel<<<BGR, 256, 0, stream>>>(out_votes, out);
}